// Round 12
// baseline (845.217 us; speedup 1.0000x reference)
//
#include <hip/hip_runtime.h>
#include <hip/hip_bf16.h>
#include <stdint.h>

#define NE 8
#define DD 2048
#define FF 4096
#define TT 4096      // tokens = 2*2048
#define NRB 1024     // router blocks (first)
#define NCV 3072     // convert blocks (1024 per tensor, 4 grid-stride iters)

typedef __attribute__((ext_vector_type(8))) short bf16x8;
typedef __attribute__((ext_vector_type(4))) float f32x4;

__device__ inline unsigned short f2bf(float f) {
  union { float f; unsigned u; } x; x.f = f;
  unsigned r = x.u + 0x7fffu + ((x.u >> 16) & 1u);
  return (unsigned short)(r >> 16);
}
__device__ inline float bf2f(unsigned short v) {
  union { unsigned u; float f; } x; x.u = (unsigned)v << 16; return x.f;
}

// fully-coalesced convert chunk of 16384 elems: 16 slices of 1024
// (loads lane-stride 16B, stores lane-stride 8B; full coverage: 16*1024=16384)
__device__ __forceinline__ void convw(const float* __restrict__ src,
                                      unsigned short* __restrict__ dst,
                                      long base, int tid) {
  float4 v[16];
#pragma unroll
  for (int j = 0; j < 16; j++)
    v[j] = *(const float4*)(src + base + j * 1024 + tid * 4);
#pragma unroll
  for (int j = 0; j < 16; j++) {
    ushort4 o;
    o.x = f2bf(v[j].x); o.y = f2bf(v[j].y); o.z = f2bf(v[j].z); o.w = f2bf(v[j].w);
    *(ushort4*)(dst + base + j * 1024 + tid * 4) = o;
  }
}

#define GLL16(g, l) __builtin_amdgcn_global_load_lds( \
    (__attribute__((address_space(1))) void*)(void*)(g), \
    (__attribute__((address_space(3))) void*)(l), 16, 0, 0)

// ---------------- router body (one wave = one token) ----------------
__device__ __forceinline__ void router_one(
    int t, int lane, const float* __restrict__ h, const float* __restrict__ gw,
    float* __restrict__ logits, unsigned short* __restrict__ hb,
    int* __restrict__ counts, int* __restrict__ tok_idx,
    int* __restrict__ sel_e, int* __restrict__ sel_slot, float* __restrict__ sel_w) {
  const float4* hr = (const float4*)(h + (size_t)t * DD);
  float4 hv[8];
  float acc[NE];
#pragma unroll
  for (int e = 0; e < NE; e++) acc[e] = 0.f;
#pragma unroll
  for (int j = 0; j < 8; j++) hv[j] = hr[j * 64 + lane];
  ushort4* hbr = (ushort4*)(hb + (size_t)t * DD);
#pragma unroll
  for (int j = 0; j < 8; j++) {
    ushort4 o;
    o.x = f2bf(hv[j].x); o.y = f2bf(hv[j].y); o.z = f2bf(hv[j].z); o.w = f2bf(hv[j].w);
    hbr[j * 64 + lane] = o;
  }
#pragma unroll
  for (int e = 0; e < NE; e++) {
    const float4* g = (const float4*)(gw + (size_t)e * DD);
    float a = 0.f;
#pragma unroll
    for (int j = 0; j < 8; j++) {
      float4 gv = g[j * 64 + lane];
      a += hv[j].x * gv.x + hv[j].y * gv.y + hv[j].z * gv.z + hv[j].w * gv.w;
    }
    acc[e] = a;
  }
#pragma unroll
  for (int e = 0; e < NE; e++) {
    float v = acc[e];
#pragma unroll
    for (int o = 32; o > 0; o >>= 1) v += __shfl_xor(v, o, 64);
    acc[e] = v;
  }
  if (lane == 0) {
#pragma unroll
    for (int e = 0; e < NE; e++) logits[(size_t)t * NE + e] = acc[e];
    int e1 = 0; float m1 = acc[0];
#pragma unroll
    for (int e = 1; e < NE; e++) if (acc[e] > m1) { m1 = acc[e]; e1 = e; }
    int e2 = -1; float m2 = -3.4e38f;
#pragma unroll
    for (int e = 0; e < NE; e++) if (e != e1 && acc[e] > m2) { m2 = acc[e]; e2 = e; }
    float s = expf(m2 - m1);
    float wa = 1.f / (1.f + s);
    float wb = s * wa;
    int s1 = atomicAdd(&counts[e1], 1);
    tok_idx[e1 * TT + s1] = t;
    int s2 = atomicAdd(&counts[e2], 1);
    tok_idx[e2 * TT + s2] = t;
    sel_e[2 * t] = e1; sel_slot[2 * t] = s1; sel_w[2 * t] = wa;
    sel_e[2 * t + 1] = e2; sel_slot[2 * t + 1] = s2; sel_w[2 * t + 1] = wb;
  }
}

// ---------------- prep: router (first) + coalesced w1/w3/w2 convert ----------------
__global__ __launch_bounds__(256) void prep_kernel(
    const float* __restrict__ h, const float* __restrict__ gw,
    float* __restrict__ logits, unsigned short* __restrict__ hb,
    int* __restrict__ counts, int* __restrict__ tok_idx,
    int* __restrict__ sel_e, int* __restrict__ sel_slot, float* __restrict__ sel_w,
    const float* __restrict__ w1, unsigned short* __restrict__ w1b,
    const float* __restrict__ w3, unsigned short* __restrict__ w3b,
    const float* __restrict__ w2, unsigned short* __restrict__ w2b) {
  int b = blockIdx.x;
  int tid = threadIdx.x;
  if (b < NRB) {
    router_one(b * 4 + (tid >> 6), tid & 63,
               h, gw, logits, hb, counts, tok_idx, sel_e, sel_slot, sel_w);
    return;
  }
  int cb = b - NRB;              // 0..3071
  int t = cb >> 10;              // tensor 0..2
  int lb = cb & 1023;            // 0..1023
  const float* src = (t == 0) ? w1 : (t == 1) ? w3 : w2;
  unsigned short* dst = (t == 0) ? w1b : (t == 1) ? w3b : w2b;
#pragma unroll
  for (int it = 0; it < 4; it++) {
    long base = (long)(it * 1024 + lb) * 16384;   // 4096 chunks x 16384 elems = 67.1M
    convw(src, dst, base, tid);
  }
}

__global__ void offsets_kernel(const int* __restrict__ counts, int* __restrict__ offsets) {
  if (threadIdx.x == 0) {
    int r = 0;
    for (int e = 0; e < NE; e++) { offsets[e] = r; r += counts[e]; }
  }
}

// =========================================================================
// Round-4 proven GEMM structure (m97-class): 2-barrier K-loop, all operands
// bf16 via global_load_lds with pre-swizzled sources, 256 threads, 32KB LDS.
// =========================================================================

// ---- gemm1: gated = silu(X w1^T) * (X w3^T), tile 128(M) x 64(F), BK=64 ----
// grid: 16384 = x(8) * m(32) * q(64); p = x+8q -> n = p&63, e = p>>6
__global__ __launch_bounds__(256) void gemm1_kernel(
    const unsigned short* __restrict__ w1b, const unsigned short* __restrict__ w3b,
    const unsigned short* __restrict__ hb, const int* __restrict__ tok_idx,
    const int* __restrict__ counts, const int* __restrict__ offsets,
    unsigned short* __restrict__ gated) {
  __shared__ __align__(16) char lds[32768];
  char* Ab = lds;              // 128 rows x 128B (bf16)
  char* B1 = lds + 16384;      // 64 rows x 128B
  char* B3 = lds + 24576;      // 64 rows x 128B

  int bid = blockIdx.x;
  int x = bid & 7;
  int rest = bid >> 3;
  int m = rest & 31;
  int q = rest >> 5;
  int p = x + 8 * q;
  int n = p & 63;
  int e = p >> 6;
  int cnt = counts[e];
  int row0 = m * 128;
  if (row0 >= cnt) return;
  int offe = offsets[e];
  int tid = threadIdx.x;

  long asrc[4];
#pragma unroll
  for (int i = 0; i < 4; i++) {
    int r = i * 32 + (tid >> 3);
    int rr = row0 + r; if (rr >= cnt) rr = cnt - 1;
    int tok = tok_idx[e * TT + rr];
    asrc[i] = (long)tok * DD + (((tid & 7) ^ (r & 7)) * 8);
  }
  int fbase = n * 64;
  long ebase = (long)e * FF * DD;
  long bsrc[2];
#pragma unroll
  for (int i = 0; i < 2; i++) {
    int r = i * 32 + (tid >> 3);
    bsrc[i] = ebase + (long)(fbase + r) * DD + (((tid & 7) ^ (r & 7)) * 8);
  }

  f32x4 acc1[4][2], acc3[4][2];
#pragma unroll
  for (int i = 0; i < 4; i++)
#pragma unroll
    for (int j = 0; j < 2; j++) { acc1[i][j] = (f32x4){0,0,0,0}; acc3[i][j] = (f32x4){0,0,0,0}; }

  int wv = tid >> 6;
  int lane = tid & 63;
  int wr = (wv >> 1) * 64;
  int wc = (wv & 1) * 32;
  int lrow = lane & 15;
  int lk4 = lane >> 4;

  for (int k0 = 0; k0 < DD; k0 += 64) {
    if (k0) __syncthreads();
#pragma unroll
    for (int i = 0; i < 4; i++)
      GLL16(hb + asrc[i] + k0, Ab + i * 4096 + tid * 16);
#pragma unroll
    for (int i = 0; i < 2; i++) {
      GLL16(w1b + bsrc[i] + k0, B1 + i * 4096 + tid * 16);
      GLL16(w3b + bsrc[i] + k0, B3 + i * 4096 + tid * 16);
    }
    __syncthreads();
#pragma unroll
    for (int kk = 0; kk < 2; kk++) {
      int kseg = kk * 4 + lk4;
      bf16x8 af[4], b1f[2], b3f[2];
#pragma unroll
      for (int i = 0; i < 4; i++) {
        int row = wr + i * 16 + lrow;
        af[i] = *(const bf16x8*)(Ab + row * 128 + ((kseg ^ (row & 7)) * 16));
      }
#pragma unroll
      for (int j = 0; j < 2; j++) {
        int row = wc + j * 16 + lrow;
        int off = row * 128 + ((kseg ^ (row & 7)) * 16);
        b1f[j] = *(const bf16x8*)(B1 + off);
        b3f[j] = *(const bf16x8*)(B3 + off);
      }
#pragma unroll
      for (int i = 0; i < 4; i++)
#pragma unroll
        for (int j = 0; j < 2; j++) {
          acc1[i][j] = __builtin_amdgcn_mfma_f32_16x16x32_bf16(af[i], b1f[j], acc1[i][j], 0, 0, 0);
          acc3[i][j] = __builtin_amdgcn_mfma_f32_16x16x32_bf16(af[i], b3f[j], acc3[i][j], 0, 0, 0);
        }
    }
  }
  // epilogue: silu(c1)*c3 -> bf16
  int crow0 = wr + (lane >> 4) * 4;
  int ccol0 = wc + (lane & 15);
#pragma unroll
  for (int i = 0; i < 4; i++)
#pragma unroll
    for (int j = 0; j < 2; j++)
#pragma unroll
      for (int r = 0; r < 4; r++) {
        int trow = crow0 + i * 16 + r;
        if (row0 + trow < cnt) {
          float g = acc1[i][j][r];
          float sg = g / (1.f + __expf(-g));
          float val = sg * acc3[i][j][r];
          gated[(size_t)(offe + row0 + trow) * FF + (fbase + ccol0 + j * 16)] = f2bf(val);
        }
      }
}

// ---- gemm2: eout(bf16) = gated w2^T, tile 128(M) x 128(D), BK=64, K=FF ----
// grid: 4096 = x(8) * m(32) * q(16); p = x+8q -> n = p&15, e = p>>4
__global__ __launch_bounds__(256) void gemm2_kernel(
    const unsigned short* __restrict__ w2b, const unsigned short* __restrict__ gated,
    const int* __restrict__ counts, const int* __restrict__ offsets,
    unsigned short* __restrict__ eout) {
  __shared__ __align__(16) char lds[32768];
  char* Ab = lds;              // 128 rows x 128B (bf16)
  char* Bb = lds + 16384;      // 128 rows x 128B

  int bid = blockIdx.x;
  int x = bid & 7;
  int rest = bid >> 3;
  int m = rest & 31;
  int q = rest >> 5;
  int p = x + 8 * q;
  int n = p & 15;
  int e = p >> 4;
  int cnt = counts[e];
  int row0 = m * 128;
  if (row0 >= cnt) return;
  int offe = offsets[e];
  int tid = threadIdx.x;

  long asrc[4];
#pragma unroll
  for (int i = 0; i < 4; i++) {
    int r = i * 32 + (tid >> 3);
    int rr = row0 + r; if (rr >= cnt) rr = cnt - 1;
    asrc[i] = (long)(offe + rr) * FF + (((tid & 7) ^ (r & 7)) * 8);
  }
  int dbase = n * 128;
  long ebase = (long)e * DD * FF;
  long bsrc[4];
#pragma unroll
  for (int i = 0; i < 4; i++) {
    int r = i * 32 + (tid >> 3);
    bsrc[i] = ebase + (long)(dbase + r) * FF + (((tid & 7) ^ (r & 7)) * 8);
  }

  f32x4 acc[4][4];
#pragma unroll
  for (int i = 0; i < 4; i++)
#pragma unroll
    for (int j = 0; j < 4; j++) acc[i][j] = (f32x4){0,0,0,0};

  int wv = tid >> 6;
  int lane = tid & 63;
  int wr = (wv >> 1) * 64;
  int wc = (wv & 1) * 64;
  int lrow = lane & 15;
  int lk4 = lane >> 4;

  for (int k0 = 0; k0 < FF; k0 += 64) {
    if (k0) __syncthreads();
#pragma unroll
    for (int i = 0; i < 4; i++)
      GLL16(gated + asrc[i] + k0, Ab + i * 4096 + tid * 16);
#pragma unroll
    for (int i = 0; i < 4; i++)
      GLL16(w2b + bsrc[i] + k0, Bb + i * 4096 + tid * 16);
    __syncthreads();
#pragma unroll
    for (int kk = 0; kk < 2; kk++) {
      int kseg = kk * 4 + lk4;
      bf16x8 af[4], bf[4];
#pragma unroll
      for (int i = 0; i < 4; i++) {
        int row = wr + i * 16 + lrow;
        af[i] = *(const bf16x8*)(Ab + row * 128 + ((kseg ^ (row & 7)) * 16));
      }
#pragma unroll
      for (int j = 0; j < 4; j++) {
        int row = wc + j * 16 + lrow;
        bf[j] = *(const bf16x8*)(Bb + row * 128 + ((kseg ^ (row & 7)) * 16));
      }
#pragma unroll
      for (int i = 0; i < 4; i++)
#pragma unroll
        for (int j = 0; j < 4; j++)
          acc[i][j] = __builtin_amdgcn_mfma_f32_16x16x32_bf16(af[i], bf[j], acc[i][j], 0, 0, 0);
    }
  }
  int crow0 = wr + (lane >> 4) * 4;
  int ccol0 = wc + (lane & 15);
#pragma unroll
  for (int i = 0; i < 4; i++)
#pragma unroll
    for (int j = 0; j < 4; j++)
#pragma unroll
      for (int r = 0; r < 4; r++) {
        int trow = crow0 + i * 16 + r;
        if (row0 + trow < cnt)
          eout[(size_t)(offe + row0 + trow) * DD + (dbase + ccol0 + j * 16)] = f2bf(acc[i][j][r]);
      }
}

// ---------------- gather: final = sum_k w_k * eout[slot_k] (bf16 eout) ----------------
__global__ void gather_kernel(const unsigned short* __restrict__ eout, const int* __restrict__ offsets,
                              const int* __restrict__ sel_e, const int* __restrict__ sel_slot,
                              const float* __restrict__ sel_w, float* __restrict__ out) {
  int idx = blockIdx.x * 256 + threadIdx.x;
  int t = idx >> 8;            // 256 chunks of 8 per row
  int c = (idx & 255) * 8;
  int ea = sel_e[2 * t], eb = sel_e[2 * t + 1];
  long sa = (long)(offsets[ea] + sel_slot[2 * t]) * DD + c;
  long sb = (long)(offsets[eb] + sel_slot[2 * t + 1]) * DD + c;
  float wa = sel_w[2 * t], wb = sel_w[2 * t + 1];
  union { uint4 v; unsigned short h[8]; } va, vb;
  va.v = *(const uint4*)(eout + sa);
  vb.v = *(const uint4*)(eout + sb);
  float4 o0, o1;
  o0.x = wa * bf2f(va.h[0]) + wb * bf2f(vb.h[0]);
  o0.y = wa * bf2f(va.h[1]) + wb * bf2f(vb.h[1]);
  o0.z = wa * bf2f(va.h[2]) + wb * bf2f(vb.h[2]);
  o0.w = wa * bf2f(va.h[3]) + wb * bf2f(vb.h[3]);
  o1.x = wa * bf2f(va.h[4]) + wb * bf2f(vb.h[4]);
  o1.y = wa * bf2f(va.h[5]) + wb * bf2f(vb.h[5]);
  o1.z = wa * bf2f(va.h[6]) + wb * bf2f(vb.h[6]);
  o1.w = wa * bf2f(va.h[7]) + wb * bf2f(vb.h[7]);
  float* op = out + (size_t)t * DD + c;
  *(float4*)op = o0;
  *(float4*)(op + 4) = o1;
}

extern "C" void kernel_launch(void* const* d_in, const int* in_sizes, int n_in,
                              void* d_out, int out_size, void* d_ws, size_t ws_size,
                              hipStream_t stream) {
  const float* h  = (const float*)d_in[0];
  const float* gw = (const float*)d_in[1];
  const float* w1 = (const float*)d_in[2];
  const float* w2 = (const float*)d_in[3];
  const float* w3 = (const float*)d_in[4];
  float* out = (float*)d_out;
  float* logits = out + (size_t)TT * DD;

  char* wp = (char*)d_ws;
  int* counts = (int*)wp; wp += 256;
  int* offsets = (int*)wp; wp += 256;
  int* tok_idx = (int*)wp; wp += (size_t)NE * TT * 4;
  int* sel_e = (int*)wp; wp += (size_t)TT * 2 * 4;
  int* sel_slot = (int*)wp; wp += (size_t)TT * 2 * 4;
  float* sel_w = (float*)wp; wp += (size_t)TT * 2 * 4;
  unsigned short* hb = (unsigned short*)wp; wp += (size_t)TT * DD * 2;
  unsigned short* gated = (unsigned short*)wp; wp += (size_t)TT * 2 * FF * 2;
  unsigned short* eout = (unsigned short*)wp; wp += (size_t)TT * 2 * DD * 2;
  long nw = (long)NE * FF * DD;
  unsigned short* w1b = (unsigned short*)wp; wp += (size_t)nw * 2;
  unsigned short* w3b = (unsigned short*)wp; wp += (size_t)nw * 2;
  unsigned short* w2b = (unsigned short*)wp; wp += (size_t)nw * 2;
  if ((size_t)(wp - (char*)d_ws) > ws_size) return;  // scratch must fit (verified, rounds 3-10)

  hipMemsetAsync(counts, 0, 32, stream);
  prep_kernel<<<NRB + NCV, 256, 0, stream>>>(
      h, gw, logits, hb, counts, tok_idx, sel_e, sel_slot, sel_w,
      w1, w1b, w3, w3b, w2, w2b);
  offsets_kernel<<<1, 64, 0, stream>>>(counts, offsets);
  gemm1_kernel<<<8 * 32 * 64, 256, 0, stream>>>(w1b, w3b, hb, tok_idx, counts, offsets, gated);
  gemm2_kernel<<<8 * 32 * 16, 256, 0, stream>>>(w2b, gated, counts, offsets, eout);
  gather_kernel<<<TT * DD / 8 / 256, 256, 0, stream>>>(eout, offsets, sel_e, sel_slot, sel_w, out);
}

// Round 13
// 778.518 us; speedup vs baseline: 1.0857x; 1.0857x over previous
//
#include <hip/hip_runtime.h>
#include <hip/hip_bf16.h>
#include <stdint.h>

#define NE 8
#define DD 2048
#define FF 4096
#define TT 4096      // tokens = 2*2048
#define NCVB 2048    // convert blocks (grid-stride, copy-shaped)

typedef __attribute__((ext_vector_type(8))) short bf16x8;
typedef __attribute__((ext_vector_type(4))) float f32x4;

__device__ inline unsigned short f2bf(float f) {
  union { float f; unsigned u; } x; x.f = f;
  unsigned r = x.u + 0x7fffu + ((x.u >> 16) & 1u);
  return (unsigned short)(r >> 16);
}
__device__ inline float bf2f(unsigned short v) {
  union { unsigned u; float f; } x; x.u = (unsigned)v << 16; return x.f;
}
__device__ inline uint4 pk8f(float4 a, float4 b) {
  union { unsigned short h[8]; uint4 v; } o;
  o.h[0] = f2bf(a.x); o.h[1] = f2bf(a.y); o.h[2] = f2bf(a.z); o.h[3] = f2bf(a.w);
  o.h[4] = f2bf(b.x); o.h[5] = f2bf(b.y); o.h[6] = f2bf(b.z); o.h[7] = f2bf(b.w);
  return o.v;
}

#define GLL16(g, l) __builtin_amdgcn_global_load_lds( \
    (__attribute__((address_space(1))) void*)(void*)(g), \
    (__attribute__((address_space(3))) void*)(l), 16, 0, 0)

// ---------------- router: logits + top2 + h->bf16 (NO atomics) ----------------
__device__ __forceinline__ void router_one(
    int t, int lane, const float* __restrict__ h, const float* __restrict__ gw,
    float* __restrict__ logits, unsigned short* __restrict__ hb,
    int* __restrict__ sel_e, float* __restrict__ sel_w) {
  const float4* hr = (const float4*)(h + (size_t)t * DD);
  float4 hv[8];
  float acc[NE];
#pragma unroll
  for (int e = 0; e < NE; e++) acc[e] = 0.f;
#pragma unroll
  for (int j = 0; j < 8; j++) hv[j] = hr[j * 64 + lane];
  ushort4* hbr = (ushort4*)(hb + (size_t)t * DD);
#pragma unroll
  for (int j = 0; j < 8; j++) {
    ushort4 o;
    o.x = f2bf(hv[j].x); o.y = f2bf(hv[j].y); o.z = f2bf(hv[j].z); o.w = f2bf(hv[j].w);
    hbr[j * 64 + lane] = o;
  }
#pragma unroll
  for (int e = 0; e < NE; e++) {
    const float4* g = (const float4*)(gw + (size_t)e * DD);
    float a = 0.f;
#pragma unroll
    for (int j = 0; j < 8; j++) {
      float4 gv = g[j * 64 + lane];
      a += hv[j].x * gv.x + hv[j].y * gv.y + hv[j].z * gv.z + hv[j].w * gv.w;
    }
    acc[e] = a;
  }
#pragma unroll
  for (int e = 0; e < NE; e++) {
    float v = acc[e];
#pragma unroll
    for (int o = 32; o > 0; o >>= 1) v += __shfl_xor(v, o, 64);
    acc[e] = v;
  }
  if (lane == 0) {
#pragma unroll
    for (int e = 0; e < NE; e++) logits[(size_t)t * NE + e] = acc[e];
    int e1 = 0; float m1 = acc[0];
#pragma unroll
    for (int e = 1; e < NE; e++) if (acc[e] > m1) { m1 = acc[e]; e1 = e; }
    int e2 = -1; float m2 = -3.4e38f;
#pragma unroll
    for (int e = 0; e < NE; e++) if (e != e1 && acc[e] > m2) { m2 = acc[e]; e2 = e; }
    float s = expf(m2 - m1);
    float wa = 1.f / (1.f + s);
    float wb = s * wa;
    sel_e[2 * t] = e1; sel_w[2 * t] = wa;
    sel_e[2 * t + 1] = e2; sel_w[2 * t + 1] = wb;
  }
}

__global__ __launch_bounds__(256) void router_kernel(
    const float* __restrict__ h, const float* __restrict__ gw,
    float* __restrict__ logits, unsigned short* __restrict__ hb,
    int* __restrict__ sel_e, float* __restrict__ sel_w) {
  router_one(blockIdx.x * 4 + (threadIdx.x >> 6), threadIdx.x & 63,
             h, gw, logits, hb, sel_e, sel_w);
}

// ---------------- build: deterministic slot assignment (1 block, no atomics) ----------------
__global__ __launch_bounds__(256) void build_kernel(
    const int* __restrict__ sel_e, int* __restrict__ counts, int* __restrict__ offsets,
    int* __restrict__ tok_idx, int* __restrict__ sel_slot) {
  __shared__ int cnt[256][NE];
  int tid = threadIdx.x;
  int le[32];
#pragma unroll
  for (int k = 0; k < 32; k++) le[k] = sel_e[tid * 32 + k];
  int c[NE];
#pragma unroll
  for (int e = 0; e < NE; e++) c[e] = 0;
#pragma unroll
  for (int k = 0; k < 32; k++) c[le[k]]++;
#pragma unroll
  for (int e = 0; e < NE; e++) cnt[tid][e] = c[e];
  __syncthreads();
  int pre[NE];
#pragma unroll
  for (int e = 0; e < NE; e++) pre[e] = 0;
  for (int i = 0; i < tid; i++)
#pragma unroll
    for (int e = 0; e < NE; e++) pre[e] += cnt[i][e];
  if (tid == 255) {
    int r = 0;
#pragma unroll
    for (int e = 0; e < NE; e++) {
      int tot = pre[e] + c[e];
      counts[e] = tot; offsets[e] = r; r += tot;
    }
  }
  int base_t = tid * 16;
#pragma unroll
  for (int k = 0; k < 32; k++) {
    int e = le[k];
    int s = pre[e]++;
    tok_idx[e * TT + s] = base_t + (k >> 1);
    sel_slot[tid * 32 + k] = s;
  }
}

// ---------------- convert: copy-shaped grid-stride fp32 -> bf16 ----------------
__device__ __forceinline__ void conv_stream(const float* __restrict__ src,
                                            unsigned short* __restrict__ dst,
                                            long i0, long stride) {
  // nw8 = NE*FF*DD/8 groups of 8 elems; exactly 16 iters/thread at NCVB*256 threads
#pragma unroll
  for (int it = 0; it < 8; it++) {
    long g0 = (i0 + (long)(2 * it) * stride) * 8;
    long g1 = g0 + stride * 8;
    float4 a0 = *(const float4*)(src + g0);
    float4 a1 = *(const float4*)(src + g0 + 4);
    float4 b0 = *(const float4*)(src + g1);
    float4 b1 = *(const float4*)(src + g1 + 4);
    *(uint4*)(dst + g0) = pk8f(a0, a1);
    *(uint4*)(dst + g1) = pk8f(b0, b1);
  }
}

__global__ __launch_bounds__(256) void convert_kernel(
    const float* __restrict__ w1, unsigned short* __restrict__ w1b,
    const float* __restrict__ w3, unsigned short* __restrict__ w3b,
    const float* __restrict__ w2, unsigned short* __restrict__ w2b) {
  long i0 = (long)blockIdx.x * 256 + threadIdx.x;
  long stride = (long)NCVB * 256;
  conv_stream(w1, w1b, i0, stride);
  conv_stream(w3, w3b, i0, stride);
  conv_stream(w2, w2b, i0, stride);
}

// =========================================================================
// Round-4 proven GEMM structure (m97-class): 2-barrier K-loop, all operands
// bf16 via global_load_lds with pre-swizzled sources, 256 threads, 32KB LDS.
// =========================================================================

// ---- gemm1: gated = silu(X w1^T) * (X w3^T), tile 128(M) x 64(F), BK=64 ----
// grid: 16384 = x(8) * m(32) * q(64); p = x+8q -> n = p&63, e = p>>6
__global__ __launch_bounds__(256) void gemm1_kernel(
    const unsigned short* __restrict__ w1b, const unsigned short* __restrict__ w3b,
    const unsigned short* __restrict__ hb, const int* __restrict__ tok_idx,
    const int* __restrict__ counts, const int* __restrict__ offsets,
    unsigned short* __restrict__ gated) {
  __shared__ __align__(16) char lds[32768];
  char* Ab = lds;              // 128 rows x 128B (bf16)
  char* B1 = lds + 16384;      // 64 rows x 128B
  char* B3 = lds + 24576;      // 64 rows x 128B

  int bid = blockIdx.x;
  int x = bid & 7;
  int rest = bid >> 3;
  int m = rest & 31;
  int q = rest >> 5;
  int p = x + 8 * q;
  int n = p & 63;
  int e = p >> 6;
  int cnt = counts[e];
  int row0 = m * 128;
  if (row0 >= cnt) return;
  int offe = offsets[e];
  int tid = threadIdx.x;

  long asrc[4];
#pragma unroll
  for (int i = 0; i < 4; i++) {
    int r = i * 32 + (tid >> 3);
    int rr = row0 + r; if (rr >= cnt) rr = cnt - 1;
    int tok = tok_idx[e * TT + rr];
    asrc[i] = (long)tok * DD + (((tid & 7) ^ (r & 7)) * 8);
  }
  int fbase = n * 64;
  long ebase = (long)e * FF * DD;
  long bsrc[2];
#pragma unroll
  for (int i = 0; i < 2; i++) {
    int r = i * 32 + (tid >> 3);
    bsrc[i] = ebase + (long)(fbase + r) * DD + (((tid & 7) ^ (r & 7)) * 8);
  }

  f32x4 acc1[4][2], acc3[4][2];
#pragma unroll
  for (int i = 0; i < 4; i++)
#pragma unroll
    for (int j = 0; j < 2; j++) { acc1[i][j] = (f32x4){0,0,0,0}; acc3[i][j] = (f32x4){0,0,0,0}; }

  int wv = tid >> 6;
  int lane = tid & 63;
  int wr = (wv >> 1) * 64;
  int wc = (wv & 1) * 32;
  int lrow = lane & 15;
  int lk4 = lane >> 4;

  for (int k0 = 0; k0 < DD; k0 += 64) {
    if (k0) __syncthreads();
#pragma unroll
    for (int i = 0; i < 4; i++)
      GLL16(hb + asrc[i] + k0, Ab + i * 4096 + tid * 16);
#pragma unroll
    for (int i = 0; i < 2; i++) {
      GLL16(w1b + bsrc[i] + k0, B1 + i * 4096 + tid * 16);
      GLL16(w3b + bsrc[i] + k0, B3 + i * 4096 + tid * 16);
    }
    __syncthreads();
#pragma unroll
    for (int kk = 0; kk < 2; kk++) {
      int kseg = kk * 4 + lk4;
      bf16x8 af[4], b1f[2], b3f[2];
#pragma unroll
      for (int i = 0; i < 4; i++) {
        int row = wr + i * 16 + lrow;
        af[i] = *(const bf16x8*)(Ab + row * 128 + ((kseg ^ (row & 7)) * 16));
      }
#pragma unroll
      for (int j = 0; j < 2; j++) {
        int row = wc + j * 16 + lrow;
        int off = row * 128 + ((kseg ^ (row & 7)) * 16);
        b1f[j] = *(const bf16x8*)(B1 + off);
        b3f[j] = *(const bf16x8*)(B3 + off);
      }
#pragma unroll
      for (int i = 0; i < 4; i++)
#pragma unroll
        for (int j = 0; j < 2; j++) {
          acc1[i][j] = __builtin_amdgcn_mfma_f32_16x16x32_bf16(af[i], b1f[j], acc1[i][j], 0, 0, 0);
          acc3[i][j] = __builtin_amdgcn_mfma_f32_16x16x32_bf16(af[i], b3f[j], acc3[i][j], 0, 0, 0);
        }
    }
  }
  // epilogue: silu(c1)*c3 -> bf16
  int crow0 = wr + (lane >> 4) * 4;
  int ccol0 = wc + (lane & 15);
#pragma unroll
  for (int i = 0; i < 4; i++)
#pragma unroll
    for (int j = 0; j < 2; j++)
#pragma unroll
      for (int r = 0; r < 4; r++) {
        int trow = crow0 + i * 16 + r;
        if (row0 + trow < cnt) {
          float g = acc1[i][j][r];
          float sg = g / (1.f + __expf(-g));
          float val = sg * acc3[i][j][r];
          gated[(size_t)(offe + row0 + trow) * FF + (fbase + ccol0 + j * 16)] = f2bf(val);
        }
      }
}

// ---- gemm2: eout(bf16) = gated w2^T, tile 128(M) x 128(D), BK=64, K=FF ----
// grid: 4096 = x(8) * m(32) * q(16); p = x+8q -> n = p&15, e = p>>4
__global__ __launch_bounds__(256) void gemm2_kernel(
    const unsigned short* __restrict__ w2b, const unsigned short* __restrict__ gated,
    const int* __restrict__ counts, const int* __restrict__ offsets,
    unsigned short* __restrict__ eout) {
  __shared__ __align__(16) char lds[32768];
  char* Ab = lds;              // 128 rows x 128B (bf16)
  char* Bb = lds + 16384;      // 128 rows x 128B

  int bid = blockIdx.x;
  int x = bid & 7;
  int rest = bid >> 3;
  int m = rest & 31;
  int q = rest >> 5;
  int p = x + 8 * q;
  int n = p & 15;
  int e = p >> 4;
  int cnt = counts[e];
  int row0 = m * 128;
  if (row0 >= cnt) return;
  int offe = offsets[e];
  int tid = threadIdx.x;

  long asrc[4];
#pragma unroll
  for (int i = 0; i < 4; i++) {
    int r = i * 32 + (tid >> 3);
    int rr = row0 + r; if (rr >= cnt) rr = cnt - 1;
    asrc[i] = (long)(offe + rr) * FF + (((tid & 7) ^ (r & 7)) * 8);
  }
  int dbase = n * 128;
  long ebase = (long)e * DD * FF;
  long bsrc[4];
#pragma unroll
  for (int i = 0; i < 4; i++) {
    int r = i * 32 + (tid >> 3);
    bsrc[i] = ebase + (long)(dbase + r) * FF + (((tid & 7) ^ (r & 7)) * 8);
  }

  f32x4 acc[4][4];
#pragma unroll
  for (int i = 0; i < 4; i++)
#pragma unroll
    for (int j = 0; j < 4; j++) acc[i][j] = (f32x4){0,0,0,0};

  int wv = tid >> 6;
  int lane = tid & 63;
  int wr = (wv >> 1) * 64;
  int wc = (wv & 1) * 64;
  int lrow = lane & 15;
  int lk4 = lane >> 4;

  for (int k0 = 0; k0 < FF; k0 += 64) {
    if (k0) __syncthreads();
#pragma unroll
    for (int i = 0; i < 4; i++)
      GLL16(gated + asrc[i] + k0, Ab + i * 4096 + tid * 16);
#pragma unroll
    for (int i = 0; i < 4; i++)
      GLL16(w2b + bsrc[i] + k0, Bb + i * 4096 + tid * 16);
    __syncthreads();
#pragma unroll
    for (int kk = 0; kk < 2; kk++) {
      int kseg = kk * 4 + lk4;
      bf16x8 af[4], bf[4];
#pragma unroll
      for (int i = 0; i < 4; i++) {
        int row = wr + i * 16 + lrow;
        af[i] = *(const bf16x8*)(Ab + row * 128 + ((kseg ^ (row & 7)) * 16));
      }
#pragma unroll
      for (int j = 0; j < 4; j++) {
        int row = wc + j * 16 + lrow;
        bf[j] = *(const bf16x8*)(Bb + row * 128 + ((kseg ^ (row & 7)) * 16));
      }
#pragma unroll
      for (int i = 0; i < 4; i++)
#pragma unroll
        for (int j = 0; j < 4; j++)
          acc[i][j] = __builtin_amdgcn_mfma_f32_16x16x32_bf16(af[i], bf[j], acc[i][j], 0, 0, 0);
    }
  }
  int crow0 = wr + (lane >> 4) * 4;
  int ccol0 = wc + (lane & 15);
#pragma unroll
  for (int i = 0; i < 4; i++)
#pragma unroll
    for (int j = 0; j < 4; j++)
#pragma unroll
      for (int r = 0; r < 4; r++) {
        int trow = crow0 + i * 16 + r;
        if (row0 + trow < cnt)
          eout[(size_t)(offe + row0 + trow) * DD + (dbase + ccol0 + j * 16)] = f2bf(acc[i][j][r]);
      }
}

// ---------------- gather: final = sum_k w_k * eout[slot_k] (bf16 eout) ----------------
__global__ void gather_kernel(const unsigned short* __restrict__ eout, const int* __restrict__ offsets,
                              const int* __restrict__ sel_e, const int* __restrict__ sel_slot,
                              const float* __restrict__ sel_w, float* __restrict__ out) {
  int idx = blockIdx.x * 256 + threadIdx.x;
  int t = idx >> 8;            // 256 chunks of 8 per row
  int c = (idx & 255) * 8;
  int ea = sel_e[2 * t], eb = sel_e[2 * t + 1];
  long sa = (long)(offsets[ea] + sel_slot[2 * t]) * DD + c;
  long sb = (long)(offsets[eb] + sel_slot[2 * t + 1]) * DD + c;
  float wa = sel_w[2 * t], wb = sel_w[2 * t + 1];
  union { uint4 v; unsigned short h[8]; } va, vb;
  va.v = *(const uint4*)(eout + sa);
  vb.v = *(const uint4*)(eout + sb);
  float4 o0, o1;
  o0.x = wa * bf2f(va.h[0]) + wb * bf2f(vb.h[0]);
  o0.y = wa * bf2f(va.h[1]) + wb * bf2f(vb.h[1]);
  o0.z = wa * bf2f(va.h[2]) + wb * bf2f(vb.h[2]);
  o0.w = wa * bf2f(va.h[3]) + wb * bf2f(vb.h[3]);
  o1.x = wa * bf2f(va.h[4]) + wb * bf2f(vb.h[4]);
  o1.y = wa * bf2f(va.h[5]) + wb * bf2f(vb.h[5]);
  o1.z = wa * bf2f(va.h[6]) + wb * bf2f(vb.h[6]);
  o1.w = wa * bf2f(va.h[7]) + wb * bf2f(vb.h[7]);
  float* op = out + (size_t)t * DD + c;
  *(float4*)op = o0;
  *(float4*)(op + 4) = o1;
}

extern "C" void kernel_launch(void* const* d_in, const int* in_sizes, int n_in,
                              void* d_out, int out_size, void* d_ws, size_t ws_size,
                              hipStream_t stream) {
  const float* h  = (const float*)d_in[0];
  const float* gw = (const float*)d_in[1];
  const float* w1 = (const float*)d_in[2];
  const float* w2 = (const float*)d_in[3];
  const float* w3 = (const float*)d_in[4];
  float* out = (float*)d_out;
  float* logits = out + (size_t)TT * DD;

  char* wp = (char*)d_ws;
  int* counts = (int*)wp; wp += 256;
  int* offsets = (int*)wp; wp += 256;
  int* tok_idx = (int*)wp; wp += (size_t)NE * TT * 4;
  int* sel_e = (int*)wp; wp += (size_t)TT * 2 * 4;
  int* sel_slot = (int*)wp; wp += (size_t)TT * 2 * 4;
  float* sel_w = (float*)wp; wp += (size_t)TT * 2 * 4;
  unsigned short* hb = (unsigned short*)wp; wp += (size_t)TT * DD * 2;
  unsigned short* gated = (unsigned short*)wp; wp += (size_t)TT * 2 * FF * 2;
  unsigned short* eout = (unsigned short*)wp; wp += (size_t)TT * 2 * DD * 2;
  long nw = (long)NE * FF * DD;
  unsigned short* w1b = (unsigned short*)wp; wp += (size_t)nw * 2;
  unsigned short* w3b = (unsigned short*)wp; wp += (size_t)nw * 2;
  unsigned short* w2b = (unsigned short*)wp; wp += (size_t)nw * 2;
  if ((size_t)(wp - (char*)d_ws) > ws_size) return;  // scratch must fit (verified, rounds 3-12)

  router_kernel<<<TT / 4, 256, 0, stream>>>(h, gw, logits, hb, sel_e, sel_w);
  convert_kernel<<<NCVB, 256, 0, stream>>>(w1, w1b, w3, w3b, w2, w2b);
  build_kernel<<<1, 256, 0, stream>>>(sel_e, counts, offsets, tok_idx, sel_slot);
  gemm1_kernel<<<8 * 32 * 64, 256, 0, stream>>>(w1b, w3b, hb, tok_idx, counts, offsets, gated);
  gemm2_kernel<<<8 * 32 * 16, 256, 0, stream>>>(w2b, gated, counts, offsets, eout);
  gather_kernel<<<TT * DD / 8 / 256, 256, 0, stream>>>(eout, offsets, sel_e, sel_slot, sel_w, out);
}